// Round 1
// 7755.325 us; speedup vs baseline: 1.6990x; 1.6990x over previous
//
#include <hip/hip_runtime.h>
#include <hip/hip_bf16.h>
#include <cmath>

// Problem constants
#define BATCH 16
#define SEQ 256
#define EMBED 512
#define HIDDEN 1024
#define GATES 4096       // 4*HIDDEN
#define VOCAB 32000
#define MROWS 4096       // BATCH*SEQ
#define LOGITS_SZ 131072000  // 16*256*32000
#define KC 16            // recurrent K-chunks (each 64 deep)

typedef unsigned short ushort_t;
typedef __attribute__((ext_vector_type(8))) __bf16 bf16x8;
typedef __attribute__((ext_vector_type(4))) float f32x4;

// ---------------- embedding gather ----------------
__global__ void embed_kernel(const int* __restrict__ x, const float* __restrict__ emb,
                             float* __restrict__ X0) {
    int r = blockIdx.x;            // r = s*16 + b
    int s = r >> 4, b = r & 15;
    int tok = x[b * SEQ + s];
    const float4* src = (const float4*)(emb + (size_t)tok * EMBED);
    float4* dst = (float4*)(X0 + (size_t)r * EMBED);
    for (int i = threadIdx.x; i < EMBED / 4; i += blockDim.x) dst[i] = src[i];
}

// ---------------- transpose W_hh [4096][1024] -> Wt [1024][4096] ----------------
__global__ void transpose_kernel(const float* __restrict__ W, float* __restrict__ Wt,
                                 int rows, int cols) {
    __shared__ float tile[32][33];
    int c0 = blockIdx.x * 32, r0 = blockIdx.y * 32;
    int tx = threadIdx.x & 31, ty = threadIdx.x >> 5;   // 256 threads: ty 0..7
    for (int i = ty; i < 32; i += 8)
        tile[i][tx] = W[(size_t)(r0 + i) * cols + (c0 + tx)];
    __syncthreads();
    for (int i = ty; i < 32; i += 8)
        Wt[(size_t)(c0 + i) * rows + (r0 + tx)] = tile[tx][i];
}

// ---------------- fp32 GEMM (kept for layer-input projections) ----------------
__global__ __launch_bounds__(256) void gemm_bt(
    const float* __restrict__ A, const float* __restrict__ B,
    const float* __restrict__ b1, const float* __restrict__ b2,
    float* __restrict__ C, int M, int N, int K, int perm) {
    __shared__ float As[8][128];
    __shared__ float Bs[8][128];
    int tid = threadIdx.x;
    int bm = blockIdx.y, bn = blockIdx.x;
    int arow = tid >> 1;              // 0..127
    int ak4 = (tid & 1) * 4;          // 0 or 4
    const float* Ag = A + (size_t)(bm * 128 + arow) * K + ak4;
    const float* Bg = B + (size_t)(bn * 128 + arow) * K + ak4;
    int tx = tid & 15, ty = tid >> 4;

    float acc[8][8];
#pragma unroll
    for (int i = 0; i < 8; i++)
#pragma unroll
        for (int j = 0; j < 8; j++) acc[i][j] = 0.f;

    for (int k0 = 0; k0 < K; k0 += 8) {
        float4 a4 = *(const float4*)(Ag + k0);
        float4 b4 = *(const float4*)(Bg + k0);
        __syncthreads();
        As[ak4 + 0][arow] = a4.x; As[ak4 + 1][arow] = a4.y;
        As[ak4 + 2][arow] = a4.z; As[ak4 + 3][arow] = a4.w;
        Bs[ak4 + 0][arow] = b4.x; Bs[ak4 + 1][arow] = b4.y;
        Bs[ak4 + 2][arow] = b4.z; Bs[ak4 + 3][arow] = b4.w;
        __syncthreads();
#pragma unroll
        for (int k = 0; k < 8; k++) {
            float av[8], bv[8];
            *(float4*)(av + 0) = *(const float4*)&As[k][ty * 8 + 0];
            *(float4*)(av + 4) = *(const float4*)&As[k][ty * 8 + 4];
            *(float4*)(bv + 0) = *(const float4*)&Bs[k][tx * 8 + 0];
            *(float4*)(bv + 4) = *(const float4*)&Bs[k][tx * 8 + 4];
#pragma unroll
            for (int i = 0; i < 8; i++)
#pragma unroll
                for (int j = 0; j < 8; j++) acc[i][j] += av[i] * bv[j];
        }
    }

#pragma unroll
    for (int i = 0; i < 8; i++) {
        int r = bm * 128 + ty * 8 + i;
        int orow = perm ? ((r & 15) * SEQ + (r >> 4)) : r;
#pragma unroll
        for (int j = 0; j < 8; j += 4) {
            int c = bn * 128 + tx * 8 + j;
            float4 v;
            float bb0 = (b1 ? b1[c + 0] : 0.f) + (b2 ? b2[c + 0] : 0.f);
            float bb1 = (b1 ? b1[c + 1] : 0.f) + (b2 ? b2[c + 1] : 0.f);
            float bb2 = (b1 ? b1[c + 2] : 0.f) + (b2 ? b2[c + 2] : 0.f);
            float bb3 = (b1 ? b1[c + 3] : 0.f) + (b2 ? b2[c + 3] : 0.f);
            v.x = acc[i][j + 0] + bb0;
            v.y = acc[i][j + 1] + bb1;
            v.z = acc[i][j + 2] + bb2;
            v.w = acc[i][j + 3] + bb3;
            *(float4*)&C[(size_t)orow * N + c] = v;
        }
    }
}

// ---------------- fp32 -> bf16 hi/lo split: X[r][1024] -> Y[r][2048] ----------------
__device__ __forceinline__ unsigned f2bf(float f) {
    unsigned u = __float_as_uint(f);
    return (u + 0x7FFFu + ((u >> 16) & 1u)) >> 16;   // RNE
}

__global__ __launch_bounds__(256) void conv_hilo(const float* __restrict__ X,
                                                 ushort_t* __restrict__ Y) {
    size_t r = blockIdx.x;                 // one block per row of 1024
    int k4 = threadIdx.x * 4;
    float4 v = *(const float4*)(X + r * HIDDEN + k4);
    unsigned h0 = f2bf(v.x), h1 = f2bf(v.y), h2 = f2bf(v.z), h3 = f2bf(v.w);
    unsigned l0 = f2bf(v.x - __uint_as_float(h0 << 16));
    unsigned l1 = f2bf(v.y - __uint_as_float(h1 << 16));
    unsigned l2 = f2bf(v.z - __uint_as_float(h2 << 16));
    unsigned l3 = f2bf(v.w - __uint_as_float(h3 << 16));
    uint2 hv, lv;
    hv.x = h0 | (h1 << 16); hv.y = h2 | (h3 << 16);
    lv.x = l0 | (l1 << 16); lv.y = l2 | (l3 << 16);
    *(uint2*)(Y + r * 2048 + k4) = hv;
    *(uint2*)(Y + r * 2048 + 1024 + k4) = lv;
}

// ---------------- split-bf16 MFMA GEMM ----------------
// C[orow][nBase+c] = sum_k A32[r][k]*B32[n][k] via Ah*Bh + Al*Bh + Ah*Bl.
// A: [M][2048] bf16 (hi|lo), B: [Nh][2048] bf16 (hi|lo), both K-contiguous.
// 128x128 tile, BK=32, 4 waves (2x2), 16x16x32 MFMA, 4x4 frags/wave.
__global__ __launch_bounds__(256) void gemm_bf16_mfma(
    const ushort_t* __restrict__ A, const ushort_t* __restrict__ B,
    const float* __restrict__ bias, float* __restrict__ C,
    int ldc, int nBase, int perm) {
    __shared__ __align__(16) ushort_t As[128 * 32];
    __shared__ __align__(16) ushort_t Bs[128 * 32];
    int tid = threadIdx.x;
    int lane = tid & 63, wave = tid >> 6;
    int wm = wave >> 1, wn = wave & 1;
    int bm = blockIdx.x, bn = blockIdx.y;

    f32x4 acc[4][4];
#pragma unroll
    for (int m = 0; m < 4; m++)
#pragma unroll
        for (int n = 0; n < 4; n++) acc[m][n] = (f32x4){0.f, 0.f, 0.f, 0.f};

    int srow = tid >> 1;            // 0..127: staged row
    int skh = (tid & 1) * 16;       // ushort k-offset 0/16
    const ushort_t* Abase = A + (size_t)(bm * 128 + srow) * 2048 + skh;
    const ushort_t* Bbase = B + (size_t)(bn * 128 + srow) * 2048 + skh;
    int lr = lane & 15;
    int lk = (lane >> 4) * 8;

#pragma unroll 1
    for (int seg = 0; seg < 3; seg++) {
        int aoff = (seg == 1) ? 1024 : 0;     // seg0: Ah*Bh, seg1: Al*Bh, seg2: Ah*Bl
        int boff = (seg == 2) ? 1024 : 0;
        for (int k0 = 0; k0 < 1024; k0 += 32) {
            uint4 a0 = *(const uint4*)(Abase + aoff + k0);
            uint4 a1 = *(const uint4*)(Abase + aoff + k0 + 8);
            uint4 b0 = *(const uint4*)(Bbase + boff + k0);
            uint4 b1 = *(const uint4*)(Bbase + boff + k0 + 8);
            __syncthreads();
            *(uint4*)(As + srow * 32 + skh) = a0;
            *(uint4*)(As + srow * 32 + skh + 8) = a1;
            *(uint4*)(Bs + srow * 32 + skh) = b0;
            *(uint4*)(Bs + srow * 32 + skh + 8) = b1;
            __syncthreads();
            bf16x8 af[4], bfv[4];
#pragma unroll
            for (int m = 0; m < 4; m++)
                af[m] = *(const bf16x8*)(As + (wm * 64 + m * 16 + lr) * 32 + lk);
#pragma unroll
            for (int n = 0; n < 4; n++)
                bfv[n] = *(const bf16x8*)(Bs + (wn * 64 + n * 16 + lr) * 32 + lk);
#pragma unroll
            for (int m = 0; m < 4; m++)
#pragma unroll
                for (int n = 0; n < 4; n++)
                    acc[m][n] = __builtin_amdgcn_mfma_f32_16x16x32_bf16(
                        af[m], bfv[n], acc[m][n], 0, 0, 0);
        }
    }

    // epilogue: C/D layout col=lane&15, row=(lane>>4)*4+j  [m89/m91-verified]
    int lq = lane >> 4;
#pragma unroll
    for (int n = 0; n < 4; n++) {
        int c = bn * 128 + wn * 64 + n * 16 + lr;
        float bb = bias ? bias[nBase + c] : 0.f;
#pragma unroll
        for (int m = 0; m < 4; m++) {
#pragma unroll
            for (int j = 0; j < 4; j++) {
                int r = bm * 128 + wm * 64 + m * 16 + lq * 4 + j;
                int orow = perm ? ((r & 15) * SEQ + (r >> 4)) : r;
                C[(size_t)orow * ldc + nBase + c] = acc[m][n][j] + bb;
            }
        }
    }
}

// ---------------- per-step recurrent partial GEMM ----------------
// parts[kc][b][n] = sum_{k in 64-chunk kc} ht[k][b] * Wt[k][n]
// grid (32, KC), block 256: 512 blocks -> 2 blocks/CU, 2 waves/SIMD.
__global__ __launch_bounds__(256) void lstm_gemm(
    const float* __restrict__ Wt,   // [1024][4096]
    const float* __restrict__ ht,   // [1024][16]   (h transposed)
    float* __restrict__ parts) {    // [KC][16][4096]
    int col = blockIdx.x * 128 + (threadIdx.x & 127);
    int bg = __builtin_amdgcn_readfirstlane(threadIdx.x >> 7);  // wave-uniform 0/1
    int b0 = bg * 8;
    int kc = blockIdx.y;            // 0..KC-1, K-chunk of 64

    float acc[8];
#pragma unroll
    for (int i = 0; i < 8; i++) acc[i] = 0.f;

    const float* wp = Wt + (size_t)kc * 64 * GATES + col;
    const float* hp = ht + kc * 64 * BATCH + b0;

#pragma unroll 16
    for (int k = 0; k < 64; k++) {
        float w = wp[(size_t)k * GATES];
        const float* h = hp + k * BATCH;   // wave-uniform address -> s_load
#pragma unroll
        for (int i = 0; i < 8; i++) acc[i] += h[i] * w;
    }

    float* outp = parts + ((size_t)kc * BATCH + b0) * GATES + col;
#pragma unroll
    for (int i = 0; i < 8; i++) outp[(size_t)i * GATES] = acc[i];
}

// ---------------- per-step LSTM elementwise update ----------------
// grid 256, block 64 -> 16384 threads = 16 b x 1024 j, spread over all CUs
__global__ __launch_bounds__(64) void lstm_update(
    const float* __restrict__ G,      // [4096][4096] rows (t*16+b)
    const float* __restrict__ parts,  // [KC][16][4096]
    float* __restrict__ c_state,      // [16][1024] (this layer)
    float* __restrict__ Hseq,         // [4096][1024] rows (t*16+b)
    float* __restrict__ ht,           // [1024][16]
    int t) {
    int gid = blockIdx.x * 64 + threadIdx.x;
    int b = gid >> 10, j = gid & 1023;

    float g4[4];
#pragma unroll
    for (int gi = 0; gi < 4; gi++) {
        int n = gi * HIDDEN + j;
        float s = G[((size_t)(t * BATCH + b)) * GATES + n];
#pragma unroll
        for (int p = 0; p < KC; p++)
            s += parts[((size_t)p * BATCH + b) * GATES + n];
        g4[gi] = s;
    }
    float ig = 1.f / (1.f + __expf(-g4[0]));
    float fg = 1.f / (1.f + __expf(-g4[1]));
    float gg = tanhf(g4[2]);
    float og = 1.f / (1.f + __expf(-g4[3]));
    float c = fg * c_state[gid] + ig * gg;
    c_state[gid] = c;
    float h = og * tanhf(c);
    Hseq[((size_t)(t * BATCH + b)) * HIDDEN + j] = h;
    ht[j * BATCH + b] = h;
}

// ---------------- init & tails ----------------
__global__ void init_state(const float* __restrict__ h0, const float* __restrict__ c0,
                           float* __restrict__ c_ws, float* __restrict__ ht0,
                           float* __restrict__ ht1) {
    int gid = blockIdx.x * 256 + threadIdx.x;  // 32768
    c_ws[gid] = c0[gid];
    int l = gid >> 14, b = (gid >> 10) & 15, j = gid & 1023;
    float h = h0[gid];
    float* htp = l ? ht1 : ht0;
    htp[j * BATCH + b] = h;
}

__global__ void write_tails(const float* __restrict__ Hseq0, const float* __restrict__ Hseq1,
                            const float* __restrict__ c_ws, float* __restrict__ out) {
    int gid = blockIdx.x * 256 + threadIdx.x;  // 32768
    int l = gid >> 14, b = (gid >> 10) & 15, j = gid & 1023;
    const float* H = l ? Hseq1 : Hseq0;
    out[LOGITS_SZ + gid] = H[(size_t)((SEQ - 1) * BATCH + b) * HIDDEN + j];
    out[LOGITS_SZ + 32768 + gid] = c_ws[gid];
}

// ---------------- launch ----------------
extern "C" void kernel_launch(void* const* d_in, const int* in_sizes, int n_in,
                              void* d_out, int out_size, void* d_ws, size_t ws_size,
                              hipStream_t stream) {
    const int* x = (const int*)d_in[0];
    const float* h0 = (const float*)d_in[1];
    const float* c0 = (const float*)d_in[2];
    const float* emb = (const float*)d_in[3];
    const float* W_ih0 = (const float*)d_in[4];
    const float* W_hh0 = (const float*)d_in[5];
    const float* b_ih0 = (const float*)d_in[6];
    const float* b_hh0 = (const float*)d_in[7];
    const float* W_ih1 = (const float*)d_in[8];
    const float* W_hh1 = (const float*)d_in[9];
    const float* b_ih1 = (const float*)d_in[10];
    const float* b_hh1 = (const float*)d_in[11];
    const float* fc_W = (const float*)d_in[12];
    const float* fc_b = (const float*)d_in[13];
    float* out = (float*)d_out;
    float* ws = (float*)d_ws;

    // workspace layout (float offsets)
    const size_t OFF_WT0 = 0;                                  // 4096*1024
    const size_t OFF_WT1 = OFF_WT0 + (size_t)GATES * HIDDEN;   // 4096*1024
    const size_t OFF_X0 = OFF_WT1 + (size_t)GATES * HIDDEN;    // 4096*512
    const size_t OFF_G = OFF_X0 + (size_t)MROWS * EMBED;       // 4096*4096
    const size_t OFF_H0S = OFF_G + (size_t)MROWS * GATES;      // 4096*1024
    const size_t OFF_H1S = OFF_H0S + (size_t)MROWS * HIDDEN;   // 4096*1024
    const size_t OFF_PARTS = OFF_H1S + (size_t)MROWS * HIDDEN; // KC*16*4096
    const size_t OFF_C = OFF_PARTS + (size_t)KC * BATCH * GATES;   // 2*16*1024
    const size_t OFF_HT0 = OFF_C + 2 * BATCH * HIDDEN;             // 1024*16
    const size_t OFF_HT1 = OFF_HT0 + (size_t)HIDDEN * BATCH;       // 1024*16

    // FC-phase overlays (WT0/WT1/X0/G are dead after the recurrences):
    // Whl: [16000][2048] bf16 = 16,384,000 floats at offset 0
    // Ahl: [4096][2048] bf16  =  4,194,304 floats at offset 16,384,000
    ushort_t* Whl = (ushort_t*)ws;
    ushort_t* Ahl = (ushort_t*)(ws + 16384000);

    init_state<<<128, 256, 0, stream>>>(h0, c0, ws + OFF_C, ws + OFF_HT0, ws + OFF_HT1);
    embed_kernel<<<MROWS, 128, 0, stream>>>(x, emb, ws + OFF_X0);
    transpose_kernel<<<dim3(HIDDEN / 32, GATES / 32), 256, 0, stream>>>(W_hh0, ws + OFF_WT0, GATES, HIDDEN);
    transpose_kernel<<<dim3(HIDDEN / 32, GATES / 32), 256, 0, stream>>>(W_hh1, ws + OFF_WT1, GATES, HIDDEN);

    // layer 0: input projection for all timesteps
    gemm_bt<<<dim3(GATES / 128, MROWS / 128), 256, 0, stream>>>(
        ws + OFF_X0, W_ih0, b_ih0, b_hh0, ws + OFF_G, MROWS, GATES, EMBED, 0);
    for (int t = 0; t < SEQ; t++) {
        lstm_gemm<<<dim3(32, KC), 256, 0, stream>>>(ws + OFF_WT0, ws + OFF_HT0, ws + OFF_PARTS);
        lstm_update<<<256, 64, 0, stream>>>(ws + OFF_G, ws + OFF_PARTS,
                                            ws + OFF_C, ws + OFF_H0S, ws + OFF_HT0, t);
    }

    // layer 1
    gemm_bt<<<dim3(GATES / 128, MROWS / 128), 256, 0, stream>>>(
        ws + OFF_H0S, W_ih1, b_ih1, b_hh1, ws + OFF_G, MROWS, GATES, HIDDEN, 0);
    for (int t = 0; t < SEQ; t++) {
        lstm_gemm<<<dim3(32, KC), 256, 0, stream>>>(ws + OFF_WT1, ws + OFF_HT1, ws + OFF_PARTS);
        lstm_update<<<256, 64, 0, stream>>>(ws + OFF_G, ws + OFF_PARTS,
                                            ws + OFF_C + BATCH * HIDDEN, ws + OFF_H1S,
                                            ws + OFF_HT1, t);
    }

    // FC via split-bf16 MFMA: logits[b][s][v]
    conv_hilo<<<MROWS, 256, 0, stream>>>(ws + OFF_H1S, Ahl);
    for (int half = 0; half < 2; half++) {
        conv_hilo<<<16000, 256, 0, stream>>>(fc_W + (size_t)half * 16000 * HIDDEN, Whl);
        gemm_bf16_mfma<<<dim3(MROWS / 128, 16000 / 128), 256, 0, stream>>>(
            Ahl, Whl, fc_b, out, VOCAB, half * 16000, 1);
    }

    write_tails<<<128, 256, 0, stream>>>(ws + OFF_H0S, ws + OFF_H1S, ws + OFF_C, out);
}